// Round 9
// baseline (131.848 us; speedup 1.0000x reference)
//
#include <hip/hip_runtime.h>

// out[n,c,p,y,x] = in1[n,c,y,x] - zpad(in2)[n,c, y+i-3, x+j-3],  p = i*7+j
// N=8, C=32, H=W=112 -> out [8,32,49,112,112] fp32 (629 MB write, ~26 MB read).
//
// R8 = R7 (best: 124.8 us = R3 skeleton + nt stores) + XCD-contiguous nc
// mapping + nt in1 loads. b%8 = XCD (dispatch heuristic); XCD x owns
// nc in [32x,32x+32): inputs per XCD = 3.2 MB (L2-resident, HBM-read once);
// strip-halo re-reads (6/22 rows) now hit the same XCD's L2 instead of HBM.
// in1 is never reused -> nontemporal load keeps it from evicting in2.
// Ablation history: R0 134.7, R1 172 (nt+plane-block), R2 249 (plane-block),
// R3 128.6 (+LDS staging), R4 129.6 (phase sep), R5 129.1 (plane-major
// store order), R6 234.9 (grid-stride, load-gated stores), R7 124.8 (nt).

#define HW     112
#define PLANE  12544        // 112*112
#define KK     49
#define NC_TOT 256          // 8*32
#define YB     16           // output rows per block
#define LROWS  22           // YB + 6 halo rows
#define LDSW   132          // LDS row pitch: [0..7]=0pad, [8..119]=x, [120..131]=0pad

typedef float f4 __attribute__((ext_vector_type(4)));

__global__ __launch_bounds__(448) void sub2_kernel(
    const float* __restrict__ in1,
    const float* __restrict__ in2,
    float* __restrict__ out)
{
    __shared__ float smem[LROWS * LDSW];   // 11616 B

    // XCD-contiguous mapping: XCD = b%8 owns nc range [32*xcd, 32*xcd+32)
    const int b   = blockIdx.x;            // 0..1791
    const int xcd = b & 7;
    const int idx = b >> 3;                // 0..223
    const int ncl = idx / 7;               // 0..31
    const int yb  = idx - ncl * 7;         // 0..6
    const int nc  = xcd * 32 + ncl;
    const int y0  = yb * YB;
    const int tid = threadIdx.x;

    // zero all of smem
    {
        const f4 z = {0.f, 0.f, 0.f, 0.f};
        for (int idx2 = tid; idx2 < (LROWS * LDSW) / 4; idx2 += 448)
            reinterpret_cast<f4*>(smem)[idx2] = z;
    }
    __syncthreads();

    // stage in2 rows [y0-3, y0+18] into smem data region (28 f4 per row)
    const float* b_pl = in2 + (size_t)nc * PLANE;
    for (int idx2 = tid; idx2 < LROWS * 28; idx2 += 448) {
        const int r  = idx2 / 28;
        const int c  = idx2 - r * 28;
        const int gy = y0 - 3 + r;
        if (gy >= 0 && gy < HW) {
            *reinterpret_cast<f4*>(&smem[r * LDSW + 8 + 4 * c]) =
                *reinterpret_cast<const f4*>(b_pl + gy * HW + 4 * c);
        }
    }
    __syncthreads();

    const int yl = tid / 28;               // 0..15
    const int x0 = (tid - yl * 28) * 4;    // 0..108
    const int y  = y0 + yl;

    // in1: read exactly once device-wide -> nt load (don't evict in2 from L2)
    const f4 a = __builtin_nontemporal_load(
        reinterpret_cast<const f4*>(in1 + (size_t)nc * PLANE + y * HW + x0));
    float* o_base = out + (size_t)nc * KK * PLANE + (size_t)y * HW + x0;

    #pragma unroll
    for (int i = 0; i < 7; ++i) {
        // window floats x0-4 .. x0+11 (16B-aligned ds_read_b128 x4)
        const float* wr = &smem[(yl + i) * LDSW + 4 + x0];
        const f4 w0 = *reinterpret_cast<const f4*>(wr);
        const f4 w1 = *reinterpret_cast<const f4*>(wr + 4);
        const f4 w2 = *reinterpret_cast<const f4*>(wr + 8);
        const f4 w3 = *reinterpret_cast<const f4*>(wr + 12);
        float wf[16];
        wf[0]=w0.x;  wf[1]=w0.y;  wf[2]=w0.z;  wf[3]=w0.w;
        wf[4]=w1.x;  wf[5]=w1.y;  wf[6]=w1.z;  wf[7]=w1.w;
        wf[8]=w2.x;  wf[9]=w2.y;  wf[10]=w2.z; wf[11]=w2.w;
        wf[12]=w3.x; wf[13]=w3.y; wf[14]=w3.z; wf[15]=w3.w;

        #pragma unroll
        for (int j = 0; j < 7; ++j) {
            f4 r;
            r.x = a.x - wf[j + 1];
            r.y = a.y - wf[j + 2];
            r.z = a.z - wf[j + 3];
            r.w = a.w - wf[j + 4];
            __builtin_nontemporal_store(
                r, reinterpret_cast<f4*>(o_base + (size_t)(i * 7 + j) * PLANE));
        }
    }
}

extern "C" void kernel_launch(void* const* d_in, const int* in_sizes, int n_in,
                              void* d_out, int out_size, void* d_ws, size_t ws_size,
                              hipStream_t stream) {
    const float* in1 = (const float*)d_in[0];
    const float* in2 = (const float*)d_in[1];
    float* out = (float*)d_out;

    const int blocks = NC_TOT * 7;   // 1792 = 8 XCDs * 224
    sub2_kernel<<<blocks, 448, 0, stream>>>(in1, in2, out);
}

// Round 10
// 123.869 us; speedup vs baseline: 1.0644x; 1.0644x over previous
//
#include <hip/hip_runtime.h>

// out[n,c,p,y,x] = in1[n,c,y,x] - zpad(in2)[n,c, y+i-3, x+j-3],  p = i*7+j
// N=8, C=32, H=W=112 -> out [8,32,49,112,112] fp32 (629 MB write, ~30 MB read).
//
// R9 = R7 (best: 124.8 us = R3 LDS-strip skeleton + nt stores) + XCD-contiguous
// nc mapping ONLY (R8 bundled this with an nt in1 load and regressed to 131.8;
// the nt load gates all 49 stores per thread on an L2-bypassing read -> likely
// culprit; retest mapping in isolation with plain in1 load).
// XCD x (= b%8 dispatch heuristic) owns nc in [32x, 32x+32): per-XCD input
// set = 3.2 MB (< 4MB L2), inputs HBM-read once, strip-halo re-reads L2-hit.
// Ablation ledger: R0 134.7, R1 172, R2 249, R3 128.6, R4 129.6 (phase-sep
// null), R5 129.1 (store-order null), R6 234.9, R7 124.8, R8 131.8.

#define HW     112
#define PLANE  12544        // 112*112
#define KK     49
#define NC_TOT 256          // 8*32
#define YB     16           // output rows per block
#define LROWS  22           // YB + 6 halo rows
#define LDSW   132          // LDS row pitch: [0..7]=0pad, [8..119]=x, [120..131]=0pad

typedef float f4 __attribute__((ext_vector_type(4)));

__global__ __launch_bounds__(448) void sub2_kernel(
    const float* __restrict__ in1,
    const float* __restrict__ in2,
    float* __restrict__ out)
{
    __shared__ float smem[LROWS * LDSW];   // 11616 B

    // XCD-contiguous mapping: XCD = b%8 owns nc range [32*xcd, 32*xcd+32)
    const int b   = blockIdx.x;            // 0..1791
    const int xcd = b & 7;
    const int idx = b >> 3;                // 0..223
    const int ncl = idx / 7;               // 0..31
    const int yb  = idx - ncl * 7;         // 0..6
    const int nc  = xcd * 32 + ncl;
    const int y0  = yb * YB;
    const int tid = threadIdx.x;

    // zero all of smem
    {
        const f4 z = {0.f, 0.f, 0.f, 0.f};
        for (int i2 = tid; i2 < (LROWS * LDSW) / 4; i2 += 448)
            reinterpret_cast<f4*>(smem)[i2] = z;
    }
    __syncthreads();

    // stage in2 rows [y0-3, y0+18] into smem data region (28 f4 per row)
    const float* b_pl = in2 + (size_t)nc * PLANE;
    for (int i2 = tid; i2 < LROWS * 28; i2 += 448) {
        const int r  = i2 / 28;
        const int c  = i2 - r * 28;
        const int gy = y0 - 3 + r;
        if (gy >= 0 && gy < HW) {
            *reinterpret_cast<f4*>(&smem[r * LDSW + 8 + 4 * c]) =
                *reinterpret_cast<const f4*>(b_pl + gy * HW + 4 * c);
        }
    }
    __syncthreads();

    const int yl = tid / 28;               // 0..15
    const int x0 = (tid - yl * 28) * 4;    // 0..108
    const int y  = y0 + yl;

    const f4 a = *reinterpret_cast<const f4*>(
        in1 + (size_t)nc * PLANE + y * HW + x0);
    float* o_base = out + (size_t)nc * KK * PLANE + (size_t)y * HW + x0;

    #pragma unroll
    for (int i = 0; i < 7; ++i) {
        // window floats x0-4 .. x0+11 (16B-aligned ds_read_b128 x4)
        const float* wr = &smem[(yl + i) * LDSW + 4 + x0];
        const f4 w0 = *reinterpret_cast<const f4*>(wr);
        const f4 w1 = *reinterpret_cast<const f4*>(wr + 4);
        const f4 w2 = *reinterpret_cast<const f4*>(wr + 8);
        const f4 w3 = *reinterpret_cast<const f4*>(wr + 12);
        float wf[16];
        wf[0]=w0.x;  wf[1]=w0.y;  wf[2]=w0.z;  wf[3]=w0.w;
        wf[4]=w1.x;  wf[5]=w1.y;  wf[6]=w1.z;  wf[7]=w1.w;
        wf[8]=w2.x;  wf[9]=w2.y;  wf[10]=w2.z; wf[11]=w2.w;
        wf[12]=w3.x; wf[13]=w3.y; wf[14]=w3.z; wf[15]=w3.w;

        #pragma unroll
        for (int j = 0; j < 7; ++j) {
            f4 r;
            r.x = a.x - wf[j + 1];
            r.y = a.y - wf[j + 2];
            r.z = a.z - wf[j + 3];
            r.w = a.w - wf[j + 4];
            __builtin_nontemporal_store(
                r, reinterpret_cast<f4*>(o_base + (size_t)(i * 7 + j) * PLANE));
        }
    }
}

extern "C" void kernel_launch(void* const* d_in, const int* in_sizes, int n_in,
                              void* d_out, int out_size, void* d_ws, size_t ws_size,
                              hipStream_t stream) {
    const float* in1 = (const float*)d_in[0];
    const float* in2 = (const float*)d_in[1];
    float* out = (float*)d_out;

    const int blocks = NC_TOT * 7;   // 1792 = 8 XCDs * 224
    sub2_kernel<<<blocks, 448, 0, stream>>>(in1, in2, out);
}